// Round 12
// baseline (348.795 us; speedup 1.0000x reference)
//
#include <hip/hip_runtime.h>
#include <hip/hip_bf16.h>

#define N_NODES 100000
#define N_EDGES 1000000
#define DIM 64

static const long long ND = (long long)N_NODES * DIM;  // 6,400,000

typedef float f4_t __attribute__((ext_vector_type(4)));

// d_out layout (floats):
// h1: [0, ND)  h2: [ND, 2*ND)  c1c2: [2*ND, 2*ND+128)  h3: [2*ND+128, ...)  h4: [3*ND+128, ...)

// d_ws layout (4-byte words):
#define WS_OFF1  200000            // 100001 used (region padded)
#define WS_OFF2  300004
#define WS_SORT1 400008            // payload (partition) then sorted src ids (place), 1M
#define WS_SORT2 1400008
#define WS_CSUM  2400008           // 128 floats
#define WS_BSUM  2400136           // 196: bucket counts -> exclusive bases
#define WS_BCUR  2400332           // 196: partition cursors
// raw bf16 feature tables (SHARED by both graphs -> 25.6MB gather working set):
#define WS_FB    2400640           // bf16 feat rows, 32 words/row, 3.2M words
#define WS_SB    (WS_FB + 3200000)
#define WS_END   (WS_SB + 3200000) // 8,800,640 words ~= 35 MB (well within budget)

#define NBUCK 98                   // buckets of 1024 nodes; 98*1024 >= 100000
#define PLACE_CAP 13312            // max bucket edges held in LDS (mean 10240, sd ~101)

#define CH_CONV 3125               // convert blocks: 3125*256*16 floats = 12.8M
#define CH_HIST 977                // hist blocks: 977*512 int4 >= 500000

__device__ __forceinline__ unsigned pk_bf16(float a, float b) {
    __hip_bfloat16 ha = __float2bfloat16(a), hb = __float2bfloat16(b);
    return (unsigned)(*(unsigned short*)&ha) | ((unsigned)(*(unsigned short*)&hb) << 16);
}
__device__ __forceinline__ float bf_lo(unsigned u) { return __uint_as_float(u << 16); }
__device__ __forceinline__ float bf_hi(unsigned u) { return __uint_as_float(u & 0xFFFF0000u); }

__global__ __launch_bounds__(256) void k_init(int* __restrict__ ws) {
    const int t = threadIdx.x;
    if (t < 128) ((float*)ws)[WS_CSUM + t] = 0.f;
    if (t < 196) ws[WS_BSUM + t] = 0;
    if (t == 0) {
        ws[WS_OFF1 + N_NODES] = N_EDGES;
        ws[WS_OFF2 + N_NODES] = N_EDGES;
    }
}

// FUSED f32->bf16 convert + bucket hist (role split by blockIdx.x).
// Convert is a pure stream (51MB read / 26MB write); hist is LDS-privatized
// atomics -> the two overlap on different pipes.
__global__ __launch_bounds__(256) void k_convert_hist(
    const f4_t* __restrict__ feat4, const f4_t* __restrict__ shuf4,
    const int4* __restrict__ dst1, const int4* __restrict__ dst2,
    int* __restrict__ ws) {
    const int bid = blockIdx.x;
    const int t = threadIdx.x;
    if (bid < CH_CONV) {
        const long long NF4 = ND / 4;               // 1.6M f4 per array
        const long long base = ((long long)bid * 256 + t) * 4;
        uint2* FB2 = (uint2*)(ws + WS_FB);
        uint2* SB2 = (uint2*)(ws + WS_SB);
        #pragma unroll
        for (int k = 0; k < 4; ++k) {
            const long long j = base + k;
            if (j < NF4) {
                const f4_t v = __builtin_nontemporal_load(feat4 + j);
                FB2[j] = make_uint2(pk_bf16(v.x, v.y), pk_bf16(v.z, v.w));
            } else if (j < 2 * NF4) {
                const long long jj = j - NF4;
                const f4_t v = __builtin_nontemporal_load(shuf4 + jj);
                SB2[jj] = make_uint2(pk_bf16(v.x, v.y), pk_bf16(v.z, v.w));
            }
        }
    } else {
        __shared__ int lcnt[2 * NBUCK];
        for (int i = t; i < 2 * NBUCK; i += 256) lcnt[i] = 0;
        __syncthreads();
        const int Q = N_EDGES / 4;
        const int qb = (bid - CH_CONV) * 512;
        #pragma unroll
        for (int k = 0; k < 2; ++k) {
            const int q = qb + k * 256 + t;
            if (q < 2 * Q) {
                const int4 d = (q < Q) ? dst1[q] : dst2[q - Q];
                const int gb = (q < Q) ? 0 : NBUCK;
                atomicAdd(&lcnt[gb + (d.x >> 10)], 1);
                atomicAdd(&lcnt[gb + (d.y >> 10)], 1);
                atomicAdd(&lcnt[gb + (d.z >> 10)], 1);
                atomicAdd(&lcnt[gb + (d.w >> 10)], 1);
            }
        }
        __syncthreads();
        if (t < 2 * NBUCK && lcnt[t] != 0) atomicAdd(&ws[WS_BSUM + t], lcnt[t]);
    }
}

// Segmented exclusive scan of the 2x98 bucket counts (in place) + copy to cursors.
__global__ __launch_bounds__(256) void k_bscan(int* __restrict__ ws) {
    const int t = threadIdx.x;
    const int n = 2 * NBUCK;
    __shared__ int s[256];
    s[t] = (t < n) ? ws[WS_BSUM + t] : 0;
    __syncthreads();
    for (int d = 1; d < 256; d <<= 1) {
        int v = 0;
        if (t >= d && (t < NBUCK || t - d >= NBUCK)) v = s[t - d];
        __syncthreads();
        s[t] += v;
        __syncthreads();
    }
    if (t < n) {
        const int excl = (t == 0 || t == NBUCK) ? 0 : s[t - 1];
        ws[WS_BSUM + t] = excl;
        ws[WS_BCUR + t] = excl;
    }
}

// Partition: scatter packed payloads (src | dstlocal<<17) into SORT grouped by
// bucket, via block-level range reservation (dense per-block runs -> L2-friendly).
__global__ __launch_bounds__(256) void k_partition(
    const int4* __restrict__ src1, const int4* __restrict__ dst1,
    const int4* __restrict__ src2, const int4* __restrict__ dst2,
    int* __restrict__ ws) {
    const int g = blockIdx.y;
    const int t = threadIdx.x;
    __shared__ int lcnt[NBUCK];
    __shared__ int lbase[NBUCK];
    const int4* sv4 = g ? src2 : src1;
    const int4* dv4 = g ? dst2 : dst1;
    int* sortp = ws + (g ? WS_SORT2 : WS_SORT1);
    int* bcur = ws + WS_BCUR + g * NBUCK;
    const int Q = N_EDGES / 4;

    const int q0 = blockIdx.x * 512 + t;
    const int q1 = q0 + 256;
    const bool v0 = q0 < Q, v1 = q1 < Q;
    int4 s0, d0, s1, d1;
    if (v0) { s0 = sv4[q0]; d0 = dv4[q0]; }
    if (v1) { s1 = sv4[q1]; d1 = dv4[q1]; }

    for (int i = t; i < NBUCK; i += 256) lcnt[i] = 0;
    __syncthreads();
    if (v0) {
        atomicAdd(&lcnt[d0.x >> 10], 1); atomicAdd(&lcnt[d0.y >> 10], 1);
        atomicAdd(&lcnt[d0.z >> 10], 1); atomicAdd(&lcnt[d0.w >> 10], 1);
    }
    if (v1) {
        atomicAdd(&lcnt[d1.x >> 10], 1); atomicAdd(&lcnt[d1.y >> 10], 1);
        atomicAdd(&lcnt[d1.z >> 10], 1); atomicAdd(&lcnt[d1.w >> 10], 1);
    }
    __syncthreads();
    if (t < NBUCK) lbase[t] = lcnt[t] ? atomicAdd(&bcur[t], lcnt[t]) : 0;
    __syncthreads();

#define PUT(ss, dd) { const int b_ = (dd) >> 10; \
    const int pos_ = atomicAdd(&lbase[b_], 1); \
    sortp[pos_] = (ss) | (((dd) & 1023) << 17); }
    if (v0) { PUT(s0.x, d0.x); PUT(s0.y, d0.y); PUT(s0.z, d0.z); PUT(s0.w, d0.w); }
    if (v1) { PUT(s1.x, d1.x); PUT(s1.y, d1.y); PUT(s1.z, d1.z); PUT(s1.w, d1.w); }
#undef PUT
}

// Place: one block per (bucket, graph). Bucket payloads -> LDS, per-node hist +
// exclusive scan -> off[], in-place scatter of src ids within the bucket window.
__global__ __launch_bounds__(256) void k_place(int* __restrict__ ws) {
    const int g = blockIdx.y;
    const int b = blockIdx.x;
    const int t = threadIdx.x;
    __shared__ int pl[PLACE_CAP];
    __shared__ int lcur[1024];
    __shared__ int sscan[256];

    const int base = ws[WS_BSUM + g * NBUCK + b];
    const int end = (b == NBUCK - 1) ? N_EDGES : ws[WS_BSUM + g * NBUCK + b + 1];
    int cnt = end - base;
    if (cnt > PLACE_CAP) cnt = PLACE_CAP;
    int* sortp = ws + (g ? WS_SORT2 : WS_SORT1);
    int* off = ws + (g ? WS_OFF2 : WS_OFF1);
    const int node0 = b << 10;

    for (int i = t; i < cnt; i += 256) pl[i] = sortp[base + i];
    for (int i = t; i < 1024; i += 256) lcur[i] = 0;
    __syncthreads();
    for (int i = t; i < cnt; i += 256) atomicAdd(&lcur[(pl[i] >> 17) & 1023], 1);
    __syncthreads();

    const int c0 = lcur[4 * t], c1 = lcur[4 * t + 1], c2 = lcur[4 * t + 2], c3 = lcur[4 * t + 3];
    sscan[t] = c0 + c1 + c2 + c3;
    __syncthreads();
    for (int d = 1; d < 256; d <<= 1) {
        int v = 0;
        if (t >= d) v = sscan[t - d];
        __syncthreads();
        sscan[t] += v;
        __syncthreads();
    }
    const int excl = (t == 0) ? 0 : sscan[t - 1];
    const int p0 = base + excl, p1 = p0 + c0, p2 = p1 + c1, p3 = p2 + c2;
    lcur[4 * t] = p0; lcur[4 * t + 1] = p1; lcur[4 * t + 2] = p2; lcur[4 * t + 3] = p3;
    const int idx = node0 + 4 * t;
    if (idx + 3 < N_NODES) {
        *(int4*)(off + idx) = make_int4(p0, p1, p2, p3);
    } else {
        if (idx + 0 < N_NODES) off[idx + 0] = p0;
        if (idx + 1 < N_NODES) off[idx + 1] = p1;
        if (idx + 2 < N_NODES) off[idx + 2] = p2;
        if (idx + 3 < N_NODES) off[idx + 3] = p3;
    }
    __syncthreads();
    for (int i = t; i < cnt; i += 256) {
        const int p = pl[i];
        const int pos = atomicAdd(&lcur[(p >> 17) & 1023], 1);
        sortp[pos] = p & 0x1FFFF;
    }
}

// Gather RAW bf16 rows (FB/SB shared by both graphs -> 25.6MB L3-resident set).
// One node per 8-lane group; lane sub owns dims [8sub,8sub+8); unroll-4.
// Writes raw f32 aggregates into the h regions (transform happens in k_htrans).
#define ACC2(gv, sv) \
    ag[0] += bf_lo(gv.x); ag[1] += bf_hi(gv.x); \
    ag[2] += bf_lo(gv.y); ag[3] += bf_hi(gv.y); \
    ag[4] += bf_lo(gv.z); ag[5] += bf_hi(gv.z); \
    ag[6] += bf_lo(gv.w); ag[7] += bf_hi(gv.w); \
    as[0] += bf_lo(sv.x); as[1] += bf_hi(sv.x); \
    as[2] += bf_lo(sv.y); as[3] += bf_hi(sv.y); \
    as[4] += bf_lo(sv.z); as[5] += bf_hi(sv.z); \
    as[6] += bf_lo(sv.w); as[7] += bf_hi(sv.w);

__global__ __launch_bounds__(256) void k_gather_pre(int* __restrict__ ws,
                                                    float* __restrict__ out) {
    const int g = blockIdx.y;
    const int* off    = ws + (g ? WS_OFF2 : WS_OFF1);
    const int* sorted = ws + (g ? WS_SORT2 : WS_SORT1);
    const uint4* FB = (const uint4*)(ws + WS_FB);   // 8 uint4 per row
    const uint4* SB = (const uint4*)(ws + WS_SB);
    float* h_f = out + (g ? ND : 0);
    float* h_s = out + (g ? 3 * ND + 128 : 2 * ND + 128);

    const int t = threadIdx.x;
    const int wave = t >> 6;
    const int lane = t & 63;
    const int nslot = lane >> 3;
    const int sub = lane & 7;

    const int n = blockIdx.x * 32 + wave * 8 + nslot;
    if (n >= N_NODES) return;

    float ag[8] = {0.f, 0.f, 0.f, 0.f, 0.f, 0.f, 0.f, 0.f};
    float as[8] = {0.f, 0.f, 0.f, 0.f, 0.f, 0.f, 0.f, 0.f};

    const int e0 = off[n];
    const int e1 = off[n + 1];
    int e = e0;
    for (; e + 3 < e1; e += 4) {
        const int sA = sorted[e], sB = sorted[e + 1];
        const int sC = sorted[e + 2], sD = sorted[e + 3];
        const uint4 gA = FB[sA * 8 + sub], hA = SB[sA * 8 + sub];
        const uint4 gB = FB[sB * 8 + sub], hB = SB[sB * 8 + sub];
        const uint4 gC = FB[sC * 8 + sub], hC = SB[sC * 8 + sub];
        const uint4 gD = FB[sD * 8 + sub], hD = SB[sD * 8 + sub];
        ACC2(gA, hA); ACC2(gB, hB); ACC2(gC, hC); ACC2(gD, hD);
    }
    for (; e < e1; ++e) {
        const int s = sorted[e];
        const uint4 gv = FB[s * 8 + sub], hv = SB[s * 8 + sub];
        ACC2(gv, hv);
    }

    float* pf = h_f + (long long)n * DIM + sub * 8;
    f4_t v0 = {ag[0], ag[1], ag[2], ag[3]};
    f4_t v1 = {ag[4], ag[5], ag[6], ag[7]};
    __builtin_nontemporal_store(v0, (f4_t*)pf);
    __builtin_nontemporal_store(v1, (f4_t*)(pf + 4));
    float* ps = h_s + (long long)n * DIM + sub * 8;
    f4_t u0 = {as[0], as[1], as[2], as[3]};
    f4_t u1 = {as[4], as[5], as[6], as[7]};
    __builtin_nontemporal_store(u0, (f4_t*)ps);
    __builtin_nontemporal_store(u1, (f4_t*)(ps + 4));
}

// In-place transform of the h regions: h = agg @ W_g + b_g, plus column sums
// for h1/h2. Lane j holds W_g[:,j] in 64 VGPRs; 256 agg rows staged in 64KB LDS.
// blockIdx.y: 0->h1(W1) 1->h2(W2) 2->h3(W1) 3->h4(W2).
__global__ __launch_bounds__(256) void k_htrans(int* __restrict__ ws,
                                                float* __restrict__ out,
                                                const float* __restrict__ W1,
                                                const float* __restrict__ b1,
                                                const float* __restrict__ W2,
                                                const float* __restrict__ b2) {
    const int y = blockIdx.y;
    const int g = y & 1;
    const float* W = g ? W2 : W1;
    const float* bias = g ? b2 : b1;
    float* hreg = out + (y == 0 ? 0 : y == 1 ? ND
                       : y == 2 ? 2 * ND + 128 : 3 * ND + 128);

    __shared__ float A[256 * 64];    // 64KB
    __shared__ float red[4][64];
    const int t = threadIdx.x;
    const int lane = t & 63;
    const int wave = t >> 6;

    float wc[64];
    #pragma unroll
    for (int k = 0; k < 64; ++k) wc[k] = W[k * 64 + lane];
    const float bj = bias[lane];

    const int n0 = blockIdx.x * 256;
    for (int q = t; q < 4096; q += 256) {
        const int row = q >> 4;
        const int n = n0 + row;
        f4_t v = {0.f, 0.f, 0.f, 0.f};
        if (n < N_NODES) v = *((const f4_t*)(hreg + (long long)n * DIM) + (q & 15));
        *(f4_t*)&A[q * 4] = v;
    }
    __syncthreads();

    float cs = 0.f;
    const int rbeg = wave * 64;
    for (int rr = 0; rr < 64; ++rr) {
        const int n = n0 + rbeg + rr;
        if (n >= N_NODES) break;
        const float* ap = &A[(rbeg + rr) * 64];
        float acc = bj;
        #pragma unroll
        for (int k4 = 0; k4 < 16; ++k4) {
            const f4_t a = *(const f4_t*)(ap + 4 * k4);   // LDS broadcast
            acc += a.x * wc[4 * k4] + a.y * wc[4 * k4 + 1]
                 + a.z * wc[4 * k4 + 2] + a.w * wc[4 * k4 + 3];
        }
        hreg[(long long)n * DIM + lane] = acc;           // in-place overwrite
        cs += acc;
    }

    if (y < 2) {
        red[wave][lane] = cs;
        __syncthreads();
        if (t < 64) {
            const float s = red[0][t] + red[1][t] + red[2][t] + red[3][t];
            unsafeAtomicAdd(&((float*)ws)[WS_CSUM + y * 64 + t], s);
        }
    }
}

__global__ void k_final(const float* __restrict__ ws_csum, float* __restrict__ out_c) {
    int t = threadIdx.x;  // 0..63 -> c1, 64..127 -> c2
    float m = ws_csum[t] * (1.0f / (float)N_NODES);
    out_c[t] = 1.f / (1.f + expf(-m));
}

extern "C" void kernel_launch(void* const* d_in, const int* in_sizes, int n_in,
                              void* d_out, int out_size, void* d_ws, size_t ws_size,
                              hipStream_t stream) {
    const float* feat = (const float*)d_in[0];
    const float* shuf = (const float*)d_in[1];
    const int* src1 = (const int*)d_in[2];
    const int* dst1 = (const int*)d_in[3];
    const int* src2 = (const int*)d_in[4];
    const int* dst2 = (const int*)d_in[5];
    const float* W1 = (const float*)d_in[6];
    const float* b1 = (const float*)d_in[7];
    const float* W2 = (const float*)d_in[8];
    const float* b2 = (const float*)d_in[9];

    float* out = (float*)d_out;
    int* ws = (int*)d_ws;
    float* ws_f = (float*)d_ws;
    float* c_out = out + 2 * ND;

    k_init<<<1, 256, 0, stream>>>(ws);
    k_convert_hist<<<CH_CONV + CH_HIST, 256, 0, stream>>>(
        (const f4_t*)feat, (const f4_t*)shuf, (const int4*)dst1, (const int4*)dst2, ws);
    k_bscan<<<1, 256, 0, stream>>>(ws);
    k_partition<<<dim3((N_EDGES / 4 + 511) / 512, 2), 256, 0, stream>>>(
        (const int4*)src1, (const int4*)dst1, (const int4*)src2, (const int4*)dst2, ws);
    k_place<<<dim3(NBUCK, 2), 256, 0, stream>>>(ws);
    k_gather_pre<<<dim3((N_NODES + 31) / 32, 2), 256, 0, stream>>>(ws, out);
    k_htrans<<<dim3((N_NODES + 255) / 256, 4), 256, 0, stream>>>(ws, out, W1, b1, W2, b2);
    k_final<<<1, 128, 0, stream>>>(ws_f + WS_CSUM, c_out);
}

// Round 13
// 307.830 us; speedup vs baseline: 1.1331x; 1.1331x over previous
//
#include <hip/hip_runtime.h>
#include <hip/hip_bf16.h>

#define N_NODES 100000
#define N_EDGES 1000000
#define DIM 64

static const long long ND = (long long)N_NODES * DIM;  // 6,400,000

typedef float f4_t __attribute__((ext_vector_type(4)));

// d_out layout (floats):
// h1: [0, ND)  h2: [ND, 2*ND)  c1c2: [2*ND, 2*ND+128)  h3: [2*ND+128, ...)  h4: [3*ND+128, ...)

// d_ws layout (4-byte words):
#define WS_OFF1  200000            // 100001 used (region padded)
#define WS_OFF2  300004
#define WS_SORT1 400008            // payload (partition) then sorted src ids (place), 1M
#define WS_SORT2 1400008
#define WS_CSUM  2400008           // 128 floats
#define WS_BSUM  2400136           // 196: bucket counts -> exclusive bases
#define WS_BCUR  2400332           // 196: partition cursors
// raw bf16 feature tables (SHARED by both graphs -> 25.6MB gather working set):
#define WS_FB    2400640           // bf16 feat rows, 32 words/row, 3.2M words
#define WS_SB    (WS_FB + 3200000)
#define WS_END   (WS_SB + 3200000) // 8,800,640 words ~= 35 MB

#define NBUCK 98                   // buckets of 1024 nodes; 98*1024 >= 100000
#define PLACE_CAP 13312            // max bucket edges held in LDS (mean 10240, sd ~101)

#define CH_CONV 3125               // convert blocks: 3125*256*16 floats = 12.8M
#define CH_HIST 977                // hist blocks: 977*512 int4 >= 500000

__device__ __forceinline__ unsigned pk_bf16(float a, float b) {
    __hip_bfloat16 ha = __float2bfloat16(a), hb = __float2bfloat16(b);
    return (unsigned)(*(unsigned short*)&ha) | ((unsigned)(*(unsigned short*)&hb) << 16);
}
__device__ __forceinline__ float bf_lo(unsigned u) { return __uint_as_float(u << 16); }
__device__ __forceinline__ float bf_hi(unsigned u) { return __uint_as_float(u & 0xFFFF0000u); }

__global__ __launch_bounds__(256) void k_init(int* __restrict__ ws) {
    const int t = threadIdx.x;
    if (t < 128) ((float*)ws)[WS_CSUM + t] = 0.f;
    if (t < 196) ws[WS_BSUM + t] = 0;
    if (t == 0) {
        ws[WS_OFF1 + N_NODES] = N_EDGES;
        ws[WS_OFF2 + N_NODES] = N_EDGES;
    }
}

// FUSED f32->bf16 convert + bucket hist (role split by blockIdx.x).
__global__ __launch_bounds__(256) void k_convert_hist(
    const f4_t* __restrict__ feat4, const f4_t* __restrict__ shuf4,
    const int4* __restrict__ dst1, const int4* __restrict__ dst2,
    int* __restrict__ ws) {
    const int bid = blockIdx.x;
    const int t = threadIdx.x;
    if (bid < CH_CONV) {
        const long long NF4 = ND / 4;               // 1.6M f4 per array
        const long long base = ((long long)bid * 256 + t) * 4;
        uint2* FB2 = (uint2*)(ws + WS_FB);
        uint2* SB2 = (uint2*)(ws + WS_SB);
        #pragma unroll
        for (int k = 0; k < 4; ++k) {
            const long long j = base + k;
            if (j < NF4) {
                const f4_t v = __builtin_nontemporal_load(feat4 + j);
                FB2[j] = make_uint2(pk_bf16(v.x, v.y), pk_bf16(v.z, v.w));
            } else if (j < 2 * NF4) {
                const long long jj = j - NF4;
                const f4_t v = __builtin_nontemporal_load(shuf4 + jj);
                SB2[jj] = make_uint2(pk_bf16(v.x, v.y), pk_bf16(v.z, v.w));
            }
        }
    } else {
        __shared__ int lcnt[2 * NBUCK];
        for (int i = t; i < 2 * NBUCK; i += 256) lcnt[i] = 0;
        __syncthreads();
        const int Q = N_EDGES / 4;
        const int qb = (bid - CH_CONV) * 512;
        #pragma unroll
        for (int k = 0; k < 2; ++k) {
            const int q = qb + k * 256 + t;
            if (q < 2 * Q) {
                const int4 d = (q < Q) ? dst1[q] : dst2[q - Q];
                const int gb = (q < Q) ? 0 : NBUCK;
                atomicAdd(&lcnt[gb + (d.x >> 10)], 1);
                atomicAdd(&lcnt[gb + (d.y >> 10)], 1);
                atomicAdd(&lcnt[gb + (d.z >> 10)], 1);
                atomicAdd(&lcnt[gb + (d.w >> 10)], 1);
            }
        }
        __syncthreads();
        if (t < 2 * NBUCK && lcnt[t] != 0) atomicAdd(&ws[WS_BSUM + t], lcnt[t]);
    }
}

// Segmented exclusive scan of the 2x98 bucket counts (in place) + copy to cursors.
__global__ __launch_bounds__(256) void k_bscan(int* __restrict__ ws) {
    const int t = threadIdx.x;
    const int n = 2 * NBUCK;
    __shared__ int s[256];
    s[t] = (t < n) ? ws[WS_BSUM + t] : 0;
    __syncthreads();
    for (int d = 1; d < 256; d <<= 1) {
        int v = 0;
        if (t >= d && (t < NBUCK || t - d >= NBUCK)) v = s[t - d];
        __syncthreads();
        s[t] += v;
        __syncthreads();
    }
    if (t < n) {
        const int excl = (t == 0 || t == NBUCK) ? 0 : s[t - 1];
        ws[WS_BSUM + t] = excl;
        ws[WS_BCUR + t] = excl;
    }
}

// Partition: scatter packed payloads (src | dstlocal<<17) into SORT grouped by
// bucket, via block-level range reservation (dense per-block runs -> L2-friendly).
__global__ __launch_bounds__(256) void k_partition(
    const int4* __restrict__ src1, const int4* __restrict__ dst1,
    const int4* __restrict__ src2, const int4* __restrict__ dst2,
    int* __restrict__ ws) {
    const int g = blockIdx.y;
    const int t = threadIdx.x;
    __shared__ int lcnt[NBUCK];
    __shared__ int lbase[NBUCK];
    const int4* sv4 = g ? src2 : src1;
    const int4* dv4 = g ? dst2 : dst1;
    int* sortp = ws + (g ? WS_SORT2 : WS_SORT1);
    int* bcur = ws + WS_BCUR + g * NBUCK;
    const int Q = N_EDGES / 4;

    const int q0 = blockIdx.x * 512 + t;
    const int q1 = q0 + 256;
    const bool v0 = q0 < Q, v1 = q1 < Q;
    int4 s0, d0, s1, d1;
    if (v0) { s0 = sv4[q0]; d0 = dv4[q0]; }
    if (v1) { s1 = sv4[q1]; d1 = dv4[q1]; }

    for (int i = t; i < NBUCK; i += 256) lcnt[i] = 0;
    __syncthreads();
    if (v0) {
        atomicAdd(&lcnt[d0.x >> 10], 1); atomicAdd(&lcnt[d0.y >> 10], 1);
        atomicAdd(&lcnt[d0.z >> 10], 1); atomicAdd(&lcnt[d0.w >> 10], 1);
    }
    if (v1) {
        atomicAdd(&lcnt[d1.x >> 10], 1); atomicAdd(&lcnt[d1.y >> 10], 1);
        atomicAdd(&lcnt[d1.z >> 10], 1); atomicAdd(&lcnt[d1.w >> 10], 1);
    }
    __syncthreads();
    if (t < NBUCK) lbase[t] = lcnt[t] ? atomicAdd(&bcur[t], lcnt[t]) : 0;
    __syncthreads();

#define PUT(ss, dd) { const int b_ = (dd) >> 10; \
    const int pos_ = atomicAdd(&lbase[b_], 1); \
    sortp[pos_] = (ss) | (((dd) & 1023) << 17); }
    if (v0) { PUT(s0.x, d0.x); PUT(s0.y, d0.y); PUT(s0.z, d0.z); PUT(s0.w, d0.w); }
    if (v1) { PUT(s1.x, d1.x); PUT(s1.y, d1.y); PUT(s1.z, d1.z); PUT(s1.w, d1.w); }
#undef PUT
}

// Place: one block per (bucket, graph). Bucket payloads -> LDS, per-node hist +
// exclusive scan -> off[], in-place scatter of src ids within the bucket window.
__global__ __launch_bounds__(256) void k_place(int* __restrict__ ws) {
    const int g = blockIdx.y;
    const int b = blockIdx.x;
    const int t = threadIdx.x;
    __shared__ int pl[PLACE_CAP];
    __shared__ int lcur[1024];
    __shared__ int sscan[256];

    const int base = ws[WS_BSUM + g * NBUCK + b];
    const int end = (b == NBUCK - 1) ? N_EDGES : ws[WS_BSUM + g * NBUCK + b + 1];
    int cnt = end - base;
    if (cnt > PLACE_CAP) cnt = PLACE_CAP;
    int* sortp = ws + (g ? WS_SORT2 : WS_SORT1);
    int* off = ws + (g ? WS_OFF2 : WS_OFF1);
    const int node0 = b << 10;

    for (int i = t; i < cnt; i += 256) pl[i] = sortp[base + i];
    for (int i = t; i < 1024; i += 256) lcur[i] = 0;
    __syncthreads();
    for (int i = t; i < cnt; i += 256) atomicAdd(&lcur[(pl[i] >> 17) & 1023], 1);
    __syncthreads();

    const int c0 = lcur[4 * t], c1 = lcur[4 * t + 1], c2 = lcur[4 * t + 2], c3 = lcur[4 * t + 3];
    sscan[t] = c0 + c1 + c2 + c3;
    __syncthreads();
    for (int d = 1; d < 256; d <<= 1) {
        int v = 0;
        if (t >= d) v = sscan[t - d];
        __syncthreads();
        sscan[t] += v;
        __syncthreads();
    }
    const int excl = (t == 0) ? 0 : sscan[t - 1];
    const int p0 = base + excl, p1 = p0 + c0, p2 = p1 + c1, p3 = p2 + c2;
    lcur[4 * t] = p0; lcur[4 * t + 1] = p1; lcur[4 * t + 2] = p2; lcur[4 * t + 3] = p3;
    const int idx = node0 + 4 * t;
    if (idx + 3 < N_NODES) {
        *(int4*)(off + idx) = make_int4(p0, p1, p2, p3);
    } else {
        if (idx + 0 < N_NODES) off[idx + 0] = p0;
        if (idx + 1 < N_NODES) off[idx + 1] = p1;
        if (idx + 2 < N_NODES) off[idx + 2] = p2;
        if (idx + 3 < N_NODES) off[idx + 3] = p3;
    }
    __syncthreads();
    for (int i = t; i < cnt; i += 256) {
        const int p = pl[i];
        const int pos = atomicAdd(&lcur[(p >> 17) & 1023], 1);
        sortp[pos] = p & 0x1FFFF;
    }
}

// Gather RAW bf16 rows (FB/SB shared by both graphs -> 25.6MB L3-resident set).
// One node per 8-lane group; lane sub owns dims [8sub,8sub+8); unroll-4.
// REGULAR stores (not nontemporal): k_htrans re-reads these, keep them in L3.
#define ACC2(gv, sv) \
    ag[0] += bf_lo(gv.x); ag[1] += bf_hi(gv.x); \
    ag[2] += bf_lo(gv.y); ag[3] += bf_hi(gv.y); \
    ag[4] += bf_lo(gv.z); ag[5] += bf_hi(gv.z); \
    ag[6] += bf_lo(gv.w); ag[7] += bf_hi(gv.w); \
    as[0] += bf_lo(sv.x); as[1] += bf_hi(sv.x); \
    as[2] += bf_lo(sv.y); as[3] += bf_hi(sv.y); \
    as[4] += bf_lo(sv.z); as[5] += bf_hi(sv.z); \
    as[6] += bf_lo(sv.w); as[7] += bf_hi(sv.w);

__global__ __launch_bounds__(256) void k_gather_pre(int* __restrict__ ws,
                                                    float* __restrict__ out) {
    const int g = blockIdx.y;
    const int* off    = ws + (g ? WS_OFF2 : WS_OFF1);
    const int* sorted = ws + (g ? WS_SORT2 : WS_SORT1);
    const uint4* FB = (const uint4*)(ws + WS_FB);   // 8 uint4 per row
    const uint4* SB = (const uint4*)(ws + WS_SB);
    float* h_f = out + (g ? ND : 0);
    float* h_s = out + (g ? 3 * ND + 128 : 2 * ND + 128);

    const int t = threadIdx.x;
    const int wave = t >> 6;
    const int lane = t & 63;
    const int nslot = lane >> 3;
    const int sub = lane & 7;

    const int n = blockIdx.x * 32 + wave * 8 + nslot;
    if (n >= N_NODES) return;

    float ag[8] = {0.f, 0.f, 0.f, 0.f, 0.f, 0.f, 0.f, 0.f};
    float as[8] = {0.f, 0.f, 0.f, 0.f, 0.f, 0.f, 0.f, 0.f};

    const int e0 = off[n];
    const int e1 = off[n + 1];
    int e = e0;
    for (; e + 3 < e1; e += 4) {
        const int sA = sorted[e], sB = sorted[e + 1];
        const int sC = sorted[e + 2], sD = sorted[e + 3];
        const uint4 gA = FB[sA * 8 + sub], hA = SB[sA * 8 + sub];
        const uint4 gB = FB[sB * 8 + sub], hB = SB[sB * 8 + sub];
        const uint4 gC = FB[sC * 8 + sub], hC = SB[sC * 8 + sub];
        const uint4 gD = FB[sD * 8 + sub], hD = SB[sD * 8 + sub];
        ACC2(gA, hA); ACC2(gB, hB); ACC2(gC, hC); ACC2(gD, hD);
    }
    for (; e < e1; ++e) {
        const int s = sorted[e];
        const uint4 gv = FB[s * 8 + sub], hv = SB[s * 8 + sub];
        ACC2(gv, hv);
    }

    float* pf = h_f + (long long)n * DIM + sub * 8;
    *(f4_t*)pf       = (f4_t){ag[0], ag[1], ag[2], ag[3]};
    *(f4_t*)(pf + 4) = (f4_t){ag[4], ag[5], ag[6], ag[7]};
    float* ps = h_s + (long long)n * DIM + sub * 8;
    *(f4_t*)ps       = (f4_t){as[0], as[1], as[2], as[3]};
    *(f4_t*)(ps + 4) = (f4_t){as[4], as[5], as[6], as[7]};
}

// In-place transform of the h regions: h = agg @ W_g + b_g, plus column sums
// for h1/h2. Lane j holds W_g[:,j] in 64 VGPRs; 128 rows staged in 32KB LDS
// (4 blocks/CU); 2-row unroll + 4-way split accumulators -> 8 live FMA chains
// (R12 lesson: single acc = 64-dep chain x 4cyc = 256 cyc/row, latency-bound
// at 2 blocks/CU -> 176us; this version is issue-bound).
// blockIdx.y: 0->h1(W1) 1->h2(W2) 2->h3(W1) 3->h4(W2).
__global__ __launch_bounds__(256) void k_htrans(int* __restrict__ ws,
                                                float* __restrict__ out,
                                                const float* __restrict__ W1,
                                                const float* __restrict__ b1,
                                                const float* __restrict__ W2,
                                                const float* __restrict__ b2) {
    const int y = blockIdx.y;
    const int g = y & 1;
    const float* W = g ? W2 : W1;
    const float* bias = g ? b2 : b1;
    float* hreg = out + (y == 0 ? 0 : y == 1 ? ND
                       : y == 2 ? 2 * ND + 128 : 3 * ND + 128);

    __shared__ float A[128 * 64];    // 32KB
    __shared__ float red[4][64];
    const int t = threadIdx.x;
    const int lane = t & 63;
    const int wave = t >> 6;

    float wc[64];
    #pragma unroll
    for (int k = 0; k < 64; ++k) wc[k] = W[k * 64 + lane];
    const float bj = bias[lane];

    const int n0 = blockIdx.x * 128;
    for (int q = t; q < 2048; q += 256) {
        const int row = q >> 4;
        const int n = n0 + row;
        f4_t v = {0.f, 0.f, 0.f, 0.f};
        if (n < N_NODES) v = *((const f4_t*)(hreg + (long long)n * DIM) + (q & 15));
        *(f4_t*)&A[q * 4] = v;
    }
    __syncthreads();

    float cs = 0.f;
    const int rbeg = wave * 32;
    for (int rr = 0; rr < 32; rr += 2) {
        const int nA = n0 + rbeg + rr;
        const int nB = nA + 1;
        const float* apA = &A[(rbeg + rr) * 64];
        const float* apB = apA + 64;
        float accA[4] = {0.f, 0.f, 0.f, 0.f};
        float accB[4] = {0.f, 0.f, 0.f, 0.f};
        #pragma unroll
        for (int k4 = 0; k4 < 16; ++k4) {
            const f4_t aA = *(const f4_t*)(apA + 4 * k4);   // LDS broadcast
            const f4_t aB = *(const f4_t*)(apB + 4 * k4);
            const float w0 = wc[4 * k4], w1 = wc[4 * k4 + 1];
            const float w2 = wc[4 * k4 + 2], w3 = wc[4 * k4 + 3];
            accA[k4 & 3] += aA.x * w0 + aA.y * w1 + aA.z * w2 + aA.w * w3;
            accB[k4 & 3] += aB.x * w0 + aB.y * w1 + aB.z * w2 + aB.w * w3;
        }
        const float hA = bj + ((accA[0] + accA[1]) + (accA[2] + accA[3]));
        const float hB = bj + ((accB[0] + accB[1]) + (accB[2] + accB[3]));
        if (nA < N_NODES) { hreg[(long long)nA * DIM + lane] = hA; cs += hA; }
        if (nB < N_NODES) { hreg[(long long)nB * DIM + lane] = hB; cs += hB; }
    }

    if (y < 2) {
        red[wave][lane] = cs;
        __syncthreads();
        if (t < 64) {
            const float s = red[0][t] + red[1][t] + red[2][t] + red[3][t];
            unsafeAtomicAdd(&((float*)ws)[WS_CSUM + y * 64 + t], s);
        }
    }
}

__global__ void k_final(const float* __restrict__ ws_csum, float* __restrict__ out_c) {
    int t = threadIdx.x;  // 0..63 -> c1, 64..127 -> c2
    float m = ws_csum[t] * (1.0f / (float)N_NODES);
    out_c[t] = 1.f / (1.f + expf(-m));
}

extern "C" void kernel_launch(void* const* d_in, const int* in_sizes, int n_in,
                              void* d_out, int out_size, void* d_ws, size_t ws_size,
                              hipStream_t stream) {
    const float* feat = (const float*)d_in[0];
    const float* shuf = (const float*)d_in[1];
    const int* src1 = (const int*)d_in[2];
    const int* dst1 = (const int*)d_in[3];
    const int* src2 = (const int*)d_in[4];
    const int* dst2 = (const int*)d_in[5];
    const float* W1 = (const float*)d_in[6];
    const float* b1 = (const float*)d_in[7];
    const float* W2 = (const float*)d_in[8];
    const float* b2 = (const float*)d_in[9];

    float* out = (float*)d_out;
    int* ws = (int*)d_ws;
    float* ws_f = (float*)d_ws;
    float* c_out = out + 2 * ND;

    k_init<<<1, 256, 0, stream>>>(ws);
    k_convert_hist<<<CH_CONV + CH_HIST, 256, 0, stream>>>(
        (const f4_t*)feat, (const f4_t*)shuf, (const int4*)dst1, (const int4*)dst2, ws);
    k_bscan<<<1, 256, 0, stream>>>(ws);
    k_partition<<<dim3((N_EDGES / 4 + 511) / 512, 2), 256, 0, stream>>>(
        (const int4*)src1, (const int4*)dst1, (const int4*)src2, (const int4*)dst2, ws);
    k_place<<<dim3(NBUCK, 2), 256, 0, stream>>>(ws);
    k_gather_pre<<<dim3((N_NODES + 31) / 32, 2), 256, 0, stream>>>(ws, out);
    k_htrans<<<dim3((N_NODES + 127) / 128, 4), 256, 0, stream>>>(ws, out, W1, b1, W2, b2);
    k_final<<<1, 128, 0, stream>>>(ws_f + WS_CSUM, c_out);
}

// Round 14
// 295.032 us; speedup vs baseline: 1.1822x; 1.0434x over previous
//
#include <hip/hip_runtime.h>
#include <hip/hip_bf16.h>

#define N_NODES 100000
#define N_EDGES 1000000
#define DIM 64

static const long long ND = (long long)N_NODES * DIM;  // 6,400,000

typedef float f4_t __attribute__((ext_vector_type(4)));

// d_out layout (floats):
// h1: [0, ND)  h2: [ND, 2*ND)  c1c2: [2*ND, 2*ND+128)  h3: [2*ND+128, ...)  h4: [3*ND+128, ...)

// d_ws layout (4-byte words):
#define WS_OFF1  200000            // 100001 used (region padded)
#define WS_OFF2  300004
#define WS_SORT1 400008            // payload (partition) then sorted src ids (place), 1M
#define WS_SORT2 1400008
#define WS_CSUM  2400008           // 128 floats
#define WS_BSUM  2400136           // 196: bucket counts -> exclusive bases
#define WS_BCUR  2400332           // 196: partition cursors
// raw bf16 feature tables (SHARED by both graphs -> 25.6MB gather working set):
#define WS_FB    2400640           // bf16 feat rows, 32 words/row, 3.2M words
#define WS_SB    (WS_FB + 3200000)
#define WS_END   (WS_SB + 3200000) // 8,800,640 words ~= 35 MB

#define NBUCK 98                   // buckets of 1024 nodes; 98*1024 >= 100000
#define PLACE_CAP 13312            // max bucket edges held in LDS (mean 10240, sd ~101)

#define CH_CONV 3125               // convert blocks: 3125*256*16 floats = 12.8M
#define CH_HIST 977                // hist blocks: 977*512 int4 >= 500000

__device__ __forceinline__ unsigned pk_bf16(float a, float b) {
    __hip_bfloat16 ha = __float2bfloat16(a), hb = __float2bfloat16(b);
    return (unsigned)(*(unsigned short*)&ha) | ((unsigned)(*(unsigned short*)&hb) << 16);
}
__device__ __forceinline__ float bf_lo(unsigned u) { return __uint_as_float(u << 16); }
__device__ __forceinline__ float bf_hi(unsigned u) { return __uint_as_float(u & 0xFFFF0000u); }

__global__ __launch_bounds__(256) void k_init(int* __restrict__ ws) {
    const int t = threadIdx.x;
    if (t < 128) ((float*)ws)[WS_CSUM + t] = 0.f;
    if (t < 196) ws[WS_BSUM + t] = 0;
    if (t == 0) {
        ws[WS_OFF1 + N_NODES] = N_EDGES;
        ws[WS_OFF2 + N_NODES] = N_EDGES;
    }
}

// FUSED f32->bf16 convert + bucket hist (role split by blockIdx.x).
__global__ __launch_bounds__(256) void k_convert_hist(
    const f4_t* __restrict__ feat4, const f4_t* __restrict__ shuf4,
    const int4* __restrict__ dst1, const int4* __restrict__ dst2,
    int* __restrict__ ws) {
    const int bid = blockIdx.x;
    const int t = threadIdx.x;
    if (bid < CH_CONV) {
        const long long NF4 = ND / 4;               // 1.6M f4 per array
        const long long base = ((long long)bid * 256 + t) * 4;
        uint2* FB2 = (uint2*)(ws + WS_FB);
        uint2* SB2 = (uint2*)(ws + WS_SB);
        #pragma unroll
        for (int k = 0; k < 4; ++k) {
            const long long j = base + k;
            if (j < NF4) {
                const f4_t v = __builtin_nontemporal_load(feat4 + j);
                FB2[j] = make_uint2(pk_bf16(v.x, v.y), pk_bf16(v.z, v.w));
            } else if (j < 2 * NF4) {
                const long long jj = j - NF4;
                const f4_t v = __builtin_nontemporal_load(shuf4 + jj);
                SB2[jj] = make_uint2(pk_bf16(v.x, v.y), pk_bf16(v.z, v.w));
            }
        }
    } else {
        __shared__ int lcnt[2 * NBUCK];
        for (int i = t; i < 2 * NBUCK; i += 256) lcnt[i] = 0;
        __syncthreads();
        const int Q = N_EDGES / 4;
        const int qb = (bid - CH_CONV) * 512;
        #pragma unroll
        for (int k = 0; k < 2; ++k) {
            const int q = qb + k * 256 + t;
            if (q < 2 * Q) {
                const int4 d = (q < Q) ? dst1[q] : dst2[q - Q];
                const int gb = (q < Q) ? 0 : NBUCK;
                atomicAdd(&lcnt[gb + (d.x >> 10)], 1);
                atomicAdd(&lcnt[gb + (d.y >> 10)], 1);
                atomicAdd(&lcnt[gb + (d.z >> 10)], 1);
                atomicAdd(&lcnt[gb + (d.w >> 10)], 1);
            }
        }
        __syncthreads();
        if (t < 2 * NBUCK && lcnt[t] != 0) atomicAdd(&ws[WS_BSUM + t], lcnt[t]);
    }
}

// Segmented exclusive scan of the 2x98 bucket counts (in place) + copy to cursors.
__global__ __launch_bounds__(256) void k_bscan(int* __restrict__ ws) {
    const int t = threadIdx.x;
    const int n = 2 * NBUCK;
    __shared__ int s[256];
    s[t] = (t < n) ? ws[WS_BSUM + t] : 0;
    __syncthreads();
    for (int d = 1; d < 256; d <<= 1) {
        int v = 0;
        if (t >= d && (t < NBUCK || t - d >= NBUCK)) v = s[t - d];
        __syncthreads();
        s[t] += v;
        __syncthreads();
    }
    if (t < n) {
        const int excl = (t == 0 || t == NBUCK) ? 0 : s[t - 1];
        ws[WS_BSUM + t] = excl;
        ws[WS_BCUR + t] = excl;
    }
}

// Partition: scatter packed payloads (src | dstlocal<<17) into SORT grouped by
// bucket, via block-level range reservation (dense per-block runs -> L2-friendly).
__global__ __launch_bounds__(256) void k_partition(
    const int4* __restrict__ src1, const int4* __restrict__ dst1,
    const int4* __restrict__ src2, const int4* __restrict__ dst2,
    int* __restrict__ ws) {
    const int g = blockIdx.y;
    const int t = threadIdx.x;
    __shared__ int lcnt[NBUCK];
    __shared__ int lbase[NBUCK];
    const int4* sv4 = g ? src2 : src1;
    const int4* dv4 = g ? dst2 : dst1;
    int* sortp = ws + (g ? WS_SORT2 : WS_SORT1);
    int* bcur = ws + WS_BCUR + g * NBUCK;
    const int Q = N_EDGES / 4;

    const int q0 = blockIdx.x * 512 + t;
    const int q1 = q0 + 256;
    const bool v0 = q0 < Q, v1 = q1 < Q;
    int4 s0, d0, s1, d1;
    if (v0) { s0 = sv4[q0]; d0 = dv4[q0]; }
    if (v1) { s1 = sv4[q1]; d1 = dv4[q1]; }

    for (int i = t; i < NBUCK; i += 256) lcnt[i] = 0;
    __syncthreads();
    if (v0) {
        atomicAdd(&lcnt[d0.x >> 10], 1); atomicAdd(&lcnt[d0.y >> 10], 1);
        atomicAdd(&lcnt[d0.z >> 10], 1); atomicAdd(&lcnt[d0.w >> 10], 1);
    }
    if (v1) {
        atomicAdd(&lcnt[d1.x >> 10], 1); atomicAdd(&lcnt[d1.y >> 10], 1);
        atomicAdd(&lcnt[d1.z >> 10], 1); atomicAdd(&lcnt[d1.w >> 10], 1);
    }
    __syncthreads();
    if (t < NBUCK) lbase[t] = lcnt[t] ? atomicAdd(&bcur[t], lcnt[t]) : 0;
    __syncthreads();

#define PUT(ss, dd) { const int b_ = (dd) >> 10; \
    const int pos_ = atomicAdd(&lbase[b_], 1); \
    sortp[pos_] = (ss) | (((dd) & 1023) << 17); }
    if (v0) { PUT(s0.x, d0.x); PUT(s0.y, d0.y); PUT(s0.z, d0.z); PUT(s0.w, d0.w); }
    if (v1) { PUT(s1.x, d1.x); PUT(s1.y, d1.y); PUT(s1.z, d1.z); PUT(s1.w, d1.w); }
#undef PUT
}

// Place: one block per (bucket, graph). Bucket payloads -> LDS, per-node hist +
// exclusive scan -> off[], in-place scatter of src ids within the bucket window.
__global__ __launch_bounds__(256) void k_place(int* __restrict__ ws) {
    const int g = blockIdx.y;
    const int b = blockIdx.x;
    const int t = threadIdx.x;
    __shared__ int pl[PLACE_CAP];
    __shared__ int lcur[1024];
    __shared__ int sscan[256];

    const int base = ws[WS_BSUM + g * NBUCK + b];
    const int end = (b == NBUCK - 1) ? N_EDGES : ws[WS_BSUM + g * NBUCK + b + 1];
    int cnt = end - base;
    if (cnt > PLACE_CAP) cnt = PLACE_CAP;
    int* sortp = ws + (g ? WS_SORT2 : WS_SORT1);
    int* off = ws + (g ? WS_OFF2 : WS_OFF1);
    const int node0 = b << 10;

    for (int i = t; i < cnt; i += 256) pl[i] = sortp[base + i];
    for (int i = t; i < 1024; i += 256) lcur[i] = 0;
    __syncthreads();
    for (int i = t; i < cnt; i += 256) atomicAdd(&lcur[(pl[i] >> 17) & 1023], 1);
    __syncthreads();

    const int c0 = lcur[4 * t], c1 = lcur[4 * t + 1], c2 = lcur[4 * t + 2], c3 = lcur[4 * t + 3];
    sscan[t] = c0 + c1 + c2 + c3;
    __syncthreads();
    for (int d = 1; d < 256; d <<= 1) {
        int v = 0;
        if (t >= d) v = sscan[t - d];
        __syncthreads();
        sscan[t] += v;
        __syncthreads();
    }
    const int excl = (t == 0) ? 0 : sscan[t - 1];
    const int p0 = base + excl, p1 = p0 + c0, p2 = p1 + c1, p3 = p2 + c2;
    lcur[4 * t] = p0; lcur[4 * t + 1] = p1; lcur[4 * t + 2] = p2; lcur[4 * t + 3] = p3;
    const int idx = node0 + 4 * t;
    if (idx + 3 < N_NODES) {
        *(int4*)(off + idx) = make_int4(p0, p1, p2, p3);
    } else {
        if (idx + 0 < N_NODES) off[idx + 0] = p0;
        if (idx + 1 < N_NODES) off[idx + 1] = p1;
        if (idx + 2 < N_NODES) off[idx + 2] = p2;
        if (idx + 3 < N_NODES) off[idx + 3] = p3;
    }
    __syncthreads();
    for (int i = t; i < cnt; i += 256) {
        const int p = pl[i];
        const int pos = atomicAdd(&lcur[(p >> 17) & 1023], 1);
        sortp[pos] = p & 0x1FFFF;
    }
}

// FUSED gather + transform, one graph per blockIdx.y. Phase 1: gather raw bf16
// rows (FB/SB, 25.6MB shared -> L3-resident); one node per 8-lane group, 32
// nodes/block; agg stays in registers. Phase 2: agg -> 32KB LDS; lane j loads
// W_g[:,j] into 64 VGPRs (after the barrier, so live ranges don't stack on the
// gather's); waves 0-1 transform the 32 feat rows (h_f + csum), waves 2-3 the
// 32 shuf rows (h_s). Broadcast LDS reads, 2-row unroll x 4 split accumulators
// (R13 scheme). Kills k_htrans and its 204MB agg round-trip; transform VALU
// overlaps gather latency across blocks (m114 mixed-pipe co-schedule).
#define ACC2(gv, sv) \
    ag[0] += bf_lo(gv.x); ag[1] += bf_hi(gv.x); \
    ag[2] += bf_lo(gv.y); ag[3] += bf_hi(gv.y); \
    ag[4] += bf_lo(gv.z); ag[5] += bf_hi(gv.z); \
    ag[6] += bf_lo(gv.w); ag[7] += bf_hi(gv.w); \
    as[0] += bf_lo(sv.x); as[1] += bf_hi(sv.x); \
    as[2] += bf_lo(sv.y); as[3] += bf_hi(sv.y); \
    as[4] += bf_lo(sv.z); as[5] += bf_hi(sv.z); \
    as[6] += bf_lo(sv.w); as[7] += bf_hi(sv.w);

__global__ __launch_bounds__(256) void k_gather_trans(int* __restrict__ ws,
                                                      const float* __restrict__ W1,
                                                      const float* __restrict__ b1,
                                                      const float* __restrict__ W2,
                                                      const float* __restrict__ b2,
                                                      float* __restrict__ out) {
    const int g = blockIdx.y;
    const int* off    = ws + (g ? WS_OFF2 : WS_OFF1);
    const int* sorted = ws + (g ? WS_SORT2 : WS_SORT1);
    const uint4* FB = (const uint4*)(ws + WS_FB);   // 8 uint4 per row
    const uint4* SB = (const uint4*)(ws + WS_SB);
    const float* W = g ? W2 : W1;
    const float* bias = g ? b2 : b1;
    float* h_f = out + (g ? ND : 0);
    float* h_s = out + (g ? 3 * ND + 128 : 2 * ND + 128);
    float* csum = (float*)ws + WS_CSUM + g * 64;

    __shared__ float Af[32][64];
    __shared__ float As_[32][64];
    __shared__ float red[4][64];

    const int t = threadIdx.x;
    const int wave = t >> 6;
    const int lane = t & 63;
    const int nslot = lane >> 3;
    const int sub = lane & 7;

    const int n0 = blockIdx.x * 32;
    const int lrow = wave * 8 + nslot;
    const int n = n0 + lrow;

    float ag[8] = {0.f, 0.f, 0.f, 0.f, 0.f, 0.f, 0.f, 0.f};
    float as[8] = {0.f, 0.f, 0.f, 0.f, 0.f, 0.f, 0.f, 0.f};

    if (n < N_NODES) {
        const int e0 = off[n];
        const int e1 = off[n + 1];
        int e = e0;
        for (; e + 3 < e1; e += 4) {
            const int sA = sorted[e], sB = sorted[e + 1];
            const int sC = sorted[e + 2], sD = sorted[e + 3];
            const uint4 gA = FB[sA * 8 + sub], hA = SB[sA * 8 + sub];
            const uint4 gB = FB[sB * 8 + sub], hB = SB[sB * 8 + sub];
            const uint4 gC = FB[sC * 8 + sub], hC = SB[sC * 8 + sub];
            const uint4 gD = FB[sD * 8 + sub], hD = SB[sD * 8 + sub];
            ACC2(gA, hA); ACC2(gB, hB); ACC2(gC, hC); ACC2(gD, hD);
        }
        for (; e < e1; ++e) {
            const int s = sorted[e];
            const uint4 gv = FB[s * 8 + sub], hv = SB[s * 8 + sub];
            ACC2(gv, hv);
        }
    }

    // stage agg to LDS (invalid rows hold zeros; guarded at store below)
    *(f4_t*)&Af[lrow][sub * 8]     = (f4_t){ag[0], ag[1], ag[2], ag[3]};
    *(f4_t*)&Af[lrow][sub * 8 + 4] = (f4_t){ag[4], ag[5], ag[6], ag[7]};
    *(f4_t*)&As_[lrow][sub * 8]     = (f4_t){as[0], as[1], as[2], as[3]};
    *(f4_t*)&As_[lrow][sub * 8 + 4] = (f4_t){as[4], as[5], as[6], as[7]};
    __syncthreads();

    // transform: lane j = output dim j; W column in regs (loaded post-barrier)
    float wc[64];
    #pragma unroll
    for (int k = 0; k < 64; ++k) wc[k] = W[k * 64 + lane];
    const float bj = bias[lane];

    const bool isf = wave < 2;
    const int rbase = (wave & 1) * 16;
    float* harr = isf ? h_f : h_s;
    const float (*A)[64] = isf ? Af : As_;

    float cs = 0.f;
    for (int rr = 0; rr < 16; rr += 2) {
        const int r = rbase + rr;
        const int nA = n0 + r;
        const int nB = nA + 1;
        const float* apA = A[r];
        const float* apB = A[r + 1];
        float accA[4] = {0.f, 0.f, 0.f, 0.f};
        float accB[4] = {0.f, 0.f, 0.f, 0.f};
        #pragma unroll
        for (int k4 = 0; k4 < 16; ++k4) {
            const f4_t aA = *(const f4_t*)(apA + 4 * k4);   // LDS broadcast
            const f4_t aB = *(const f4_t*)(apB + 4 * k4);
            const float w0 = wc[4 * k4], w1 = wc[4 * k4 + 1];
            const float w2 = wc[4 * k4 + 2], w3 = wc[4 * k4 + 3];
            accA[k4 & 3] += aA.x * w0 + aA.y * w1 + aA.z * w2 + aA.w * w3;
            accB[k4 & 3] += aB.x * w0 + aB.y * w1 + aB.z * w2 + aB.w * w3;
        }
        const float hA = bj + ((accA[0] + accA[1]) + (accA[2] + accA[3]));
        const float hB = bj + ((accB[0] + accB[1]) + (accB[2] + accB[3]));
        if (nA < N_NODES) {
            __builtin_nontemporal_store(hA, &harr[(long long)nA * DIM + lane]);
            cs += hA;
        }
        if (nB < N_NODES) {
            __builtin_nontemporal_store(hB, &harr[(long long)nB * DIM + lane]);
            cs += hB;
        }
    }

    // csum over h1/h2 (feat rows of both graphs): waves 0,1 carry cs
    red[wave][lane] = isf ? cs : 0.f;
    __syncthreads();
    if (t < 64) {
        const float s = red[0][t] + red[1][t];
        unsafeAtomicAdd(&csum[t], s);
    }
}

__global__ void k_final(const float* __restrict__ ws_csum, float* __restrict__ out_c) {
    int t = threadIdx.x;  // 0..63 -> c1, 64..127 -> c2
    float m = ws_csum[t] * (1.0f / (float)N_NODES);
    out_c[t] = 1.f / (1.f + expf(-m));
}

extern "C" void kernel_launch(void* const* d_in, const int* in_sizes, int n_in,
                              void* d_out, int out_size, void* d_ws, size_t ws_size,
                              hipStream_t stream) {
    const float* feat = (const float*)d_in[0];
    const float* shuf = (const float*)d_in[1];
    const int* src1 = (const int*)d_in[2];
    const int* dst1 = (const int*)d_in[3];
    const int* src2 = (const int*)d_in[4];
    const int* dst2 = (const int*)d_in[5];
    const float* W1 = (const float*)d_in[6];
    const float* b1 = (const float*)d_in[7];
    const float* W2 = (const float*)d_in[8];
    const float* b2 = (const float*)d_in[9];

    float* out = (float*)d_out;
    int* ws = (int*)d_ws;
    float* ws_f = (float*)d_ws;
    float* c_out = out + 2 * ND;

    k_init<<<1, 256, 0, stream>>>(ws);
    k_convert_hist<<<CH_CONV + CH_HIST, 256, 0, stream>>>(
        (const f4_t*)feat, (const f4_t*)shuf, (const int4*)dst1, (const int4*)dst2, ws);
    k_bscan<<<1, 256, 0, stream>>>(ws);
    k_partition<<<dim3((N_EDGES / 4 + 511) / 512, 2), 256, 0, stream>>>(
        (const int4*)src1, (const int4*)dst1, (const int4*)src2, (const int4*)dst2, ws);
    k_place<<<dim3(NBUCK, 2), 256, 0, stream>>>(ws);
    k_gather_trans<<<dim3((N_NODES + 31) / 32, 2), 256, 0, stream>>>(
        ws, W1, b1, W2, b2, out);
    k_final<<<1, 128, 0, stream>>>(ws_f + WS_CSUM, c_out);
}